// Round 15
// baseline (15760.358 us; speedup 1.0000x reference)
//
#include <hip/hip_runtime.h>
#include <hip/hip_bf16.h>

// LSTM encoder: B=64, L=2048, D=256, 4D=1024, VOCAB=6000
// R15: 4-slot GROUP ROTATION to hide transport RT.
//   4 worker CUs (bid = q = d-quadrant 0..3). Each iteration t: slots
//   G=0..3 (row groups). A slot's poll reads granules published ONE FULL
//   ITERATION earlier (~4 compute-slots ~2us) -> visible -> first-try hit.
//   The sc0sc1 MALL round trip (the 2.3us/step floor of R9/R13, exposed
//   because poll target was published only ~0 earlier) falls off the
//   critical path. R12's version of this failed by sampling B at iter TOP
//   (0 delay after producer store); here every slot's poll is ~T_iter after
//   its producers' stores.
//   U (128KB, depends on q only) shared by all 4 groups. Per-slot protocol
//   R13-verbatim: poll->stage->bA->MFMA->sg->bB->elementwise->publish.
//   sc0sc1 everywhere (R14 lesson: sc0-only is NOT cross-CU coherent).
//   Heaters on bid>=4; bounded polls; LDS 88KB -> worker CU exclusive.

#define B_     64
#define L_     2048
#define D_     256
#define G4_    1024
#define VOCAB_ 6000

typedef short    s16x8 __attribute__((ext_vector_type(8)));
typedef float    f32x4 __attribute__((ext_vector_type(4)));
typedef unsigned u32x2 __attribute__((ext_vector_type(2)));
typedef unsigned u32x4 __attribute__((ext_vector_type(4)));

// ---- ws layout (bytes) ----
#define OFF_EMBB   0u            // VOCAB*D bf16 = 3,072,000
#define OFF_WT     3072000u      // W^T bf16 (dead after xg; reused as mask8)
#define OFF_UF     3596288u      // U frag layout = 524,288
#define OFF_HTAG   4120576u      // 2 parity x 64 rows x 128 granules x 8B = 131,072
#define OFF_DONE   4251648u      // 4 worker done flags (+pad) = 64
#define OFF_XG     4251712u      // [t][g][q][em16][p32][Q4] u32 = 268,435,456
#define WS_NEED    272687168u

// ---- scan LDS (padded > 80KB -> 1 WG/CU) ----
#define HL_OFF     0             // h staging 16 rows x 512B (XOR-swizzled)
#define SG_OFF     8192          // gates f32 [4][16][66] = 16,896
#define ROLE_OFF   25600         // heater stop broadcast
#define SMEM_TOTAL 90112         // 88KB: CU-exclusivity pad

__global__ void prep_kernel(const float* __restrict__ emb,
                            const float* __restrict__ W,
                            const float* __restrict__ U,
                            __hip_bfloat16* __restrict__ embb,
                            __hip_bfloat16* __restrict__ Wt,
                            __hip_bfloat16* __restrict__ Ufrag) {
  const int stride = gridDim.x * blockDim.x;
  const int i0 = blockIdx.x * blockDim.x + threadIdx.x;
  for (int i = i0; i < VOCAB_ * D_; i += stride)
    embb[i] = __float2bfloat16(emb[i]);
  for (int i = i0; i < D_ * G4_; i += stride) {
    int k = i >> 10;
    int n = i & (G4_ - 1);
    Wt[n * D_ + k] = __float2bfloat16(W[i]);
  }
  // U frags: fr = ((q*8 + w)*2 + st)*8 + kk;  elem i = fr*512 + l*8 + j
  //   n = (w>>1)*256 + q*64 + (w&1)*32 + st*16 + (l&15)
  //   k = kk*32 + (l>>4)*8 + j
  for (int i = i0; i < 262144; i += stride) {
    int j  = i & 7;
    int l  = (i >> 3) & 63;
    int fr = i >> 9;
    int kk = fr & 7;
    int st = (fr >> 3) & 1;
    int w  = (fr >> 4) & 7;
    int qq = fr >> 7;
    int n = (w >> 1) * 256 + qq * 64 + (w & 1) * 32 + st * 16 + (l & 15);
    int k = kk * 32 + (l >> 4) * 8 + j;
    Ufrag[i] = __float2bfloat16(U[k * G4_ + n]);
  }
}

// mask8[t*64+b] = (ctx[b][t] != 0) — runs AFTER xg_kernel, overwrites Wt
__global__ void mask_kernel(const int* __restrict__ ctx,
                            unsigned char* __restrict__ m8) {
  const int stride = gridDim.x * blockDim.x;
  for (int i = blockIdx.x * blockDim.x + threadIdx.x; i < B_ * L_; i += stride) {
    int b = i & 63, t = i >> 6;
    m8[t * 64 + b] = (ctx[b * L_ + t] != 0) ? 1 : 0;
  }
}

__device__ inline unsigned pk2(float a, float b) {
  return (unsigned)__bfloat16_as_ushort(__float2bfloat16(a)) |
         ((unsigned)__bfloat16_as_ushort(__float2bfloat16(b)) << 16);
}
__device__ inline float bl(unsigned u) {
  union { unsigned u; float f; } c; c.u = u << 16; return c.f;
}
__device__ inline float bh(unsigned u) {
  union { unsigned u; float f; } c; c.u = u & 0xffff0000u; return c.f;
}
__device__ inline float fsigmoid(float x) { return 1.f / (1.f + __expf(-x)); }
__device__ inline float ftanh(float x)    { return 1.f - 2.f / (__expf(2.f * x) + 1.f); }

// ---- xg precompute: grid 512 = 32 t-chunks x 4 groups x 4 gates ----
// Output layout: xg[t][g][q][em(16)][p(32)][Q(4)] as u32 = pk2 of d-pair.
__global__ __launch_bounds__(256, 2)
void xg_kernel(const int* __restrict__ ctx,
               const __hip_bfloat16* __restrict__ embb,
               const __hip_bfloat16* __restrict__ Wt,
               unsigned* __restrict__ xgw) {
  const int bid = blockIdx.x;
  const int Q   = bid & 3;
  const int g   = (bid >> 2) & 3;
  const int tc  = bid >> 4;
  const int tid = threadIdx.x;
  const int wv  = tid >> 6;            // == quadrant q of the scan
  const int l   = tid & 63;
  const int l15 = l & 15, lhi = l >> 4;
  const int row0 = g * 16;

  s16x8 bfr[8][4];
#pragma unroll
  for (int nt = 0; nt < 4; ++nt) {
    const int n = Q * 256 + wv * 64 + nt * 16 + l15;
    const __hip_bfloat16* wp = Wt + n * D_ + lhi * 8;
#pragma unroll
    for (int kk = 0; kk < 8; ++kk)
      bfr[kk][nt] = *(const s16x8*)(wp + kk * 32);
  }

  for (int tt = 0; tt < 64; ++tt) {
    const int t = tc * 64 + tt;
    const int tok = ctx[(row0 + l15) * L_ + t];
    const __hip_bfloat16* xp = embb + tok * D_ + lhi * 8;
    s16x8 af[8];
#pragma unroll
    for (int kk = 0; kk < 8; ++kk)
      af[kk] = *(const s16x8*)(xp + kk * 32);

    f32x4 acc[4];
#pragma unroll
    for (int nt = 0; nt < 4; ++nt) acc[nt] = (f32x4){0.f, 0.f, 0.f, 0.f};
#pragma unroll
    for (int kk = 0; kk < 8; ++kk)
#pragma unroll
      for (int nt = 0; nt < 4; ++nt)
        acc[nt] = __builtin_amdgcn_mfma_f32_16x16x32_bf16(af[kk], bfr[kk][nt], acc[nt], 0, 0, 0);

    // pair adjacent cols via shfl, even-col lanes store u32 per (row, pair, Q)
#pragma unroll
    for (int nt = 0; nt < 4; ++nt)
#pragma unroll
      for (int r = 0; r < 4; ++r) {
        float nb = __shfl_xor(acc[nt][r], 1);
        if (!(l15 & 1)) {
          unsigned v = pk2(acc[nt][r], nb);
          int em = lhi * 4 + r;
          int p  = nt * 8 + (l15 >> 1);
          size_t idx = ((((size_t)(t * 4 + g) * 4 + wv) * 16 + em) * 32 + p) * 4 + Q;
          xgw[idx] = v;
        }
      }
  }
}

// ---- scan: 256 WGs x 512 thr; bid 0..3 workers (q=bid), rest heaters ----
__global__ __launch_bounds__(512, 1)
void scan_kernel(const float* __restrict__ bias,
                 const __hip_bfloat16* __restrict__ Ufrag,
                 const unsigned* __restrict__ xgw,
                 const unsigned char* __restrict__ mask8,
                 unsigned* __restrict__ donef,
                 char* __restrict__ htag,
                 float* __restrict__ out) {
  extern __shared__ __align__(16) char smem[];
  const int bid = blockIdx.x;
  const int tid = threadIdx.x;

  if (bid >= 4) {
    // ---- heater: dependent FMA chains keep DPM clocks up; exit on done
    volatile int* hd = (volatile int*)(smem + ROLE_OFF);
    if (tid == 0) *hd = 0;
    __syncthreads();
    float v0 = (float)(tid + 1), v1 = v0 * 1.1f, v2 = v0 * 1.2f, v3 = v0 * 1.3f;
    for (int it = 0; it < (1 << 15); ++it) {
#pragma unroll
      for (int kk = 0; kk < 128; ++kk) {
        v0 = __builtin_fmaf(v0, 1.0000001f, 1.0e-7f);
        v1 = __builtin_fmaf(v1, 1.0000001f, 1.0e-7f);
        v2 = __builtin_fmaf(v2, 1.0000001f, 1.0e-7f);
        v3 = __builtin_fmaf(v3, 1.0000001f, 1.0e-7f);
      }
      if (tid == 0 && (it & 15) == 0) {
        u32x4 fa;
        asm volatile("global_load_dwordx4 %0, %1, off sc0 sc1\n\t"
                     "s_waitcnt vmcnt(0)"
                     : "=&v"(fa) : "v"(donef) : "memory");
        unsigned mn = fa.x;
        mn = fa.y < mn ? fa.y : mn;
        mn = fa.z < mn ? fa.z : mn;
        mn = fa.w < mn ? fa.w : mn;
        if (mn != 0u) *hd = 1;
      }
      if (*hd) break;
    }
    asm volatile("" :: "v"(v0), "v"(v1), "v"(v2), "v"(v3));
    return;
  }

  // ---- worker: q = bid (d-quadrant); serves ALL 4 row groups per step
  const int q = bid;

  const int w   = tid >> 6;             // wave 0..7: gate Q = w>>1, half = w&1
  const int l   = tid & 63;
  const int l15 = l & 15, lhi = l >> 4;
  const int Q   = w >> 1, sgs = w & 1;
  const int em  = tid >> 5;             // elementwise row 0..15
  const int e5  = tid & 31;             // elementwise d-pair 0..31

  float* sg = (float*)(smem + SG_OFF);
  char*  hl = smem + HL_OFF;
  const s16x8* uf = (const s16x8*)Ufrag;

  // ---- U frags (shared across groups; allocator may keep or reload — both OK)
  s16x8 ur[16];
#pragma unroll
  for (int kk = 0; kk < 8; ++kk)
#pragma unroll
    for (int st = 0; st < 2; ++st)
      ur[kk * 2 + st] = uf[((((q * 8 + w) * 2 + st) * 8) + kk) * 64 + l];

  // bias: bq[Q][b] for d = q*64 + 2*e5 + b (group-independent)
  float bq[4][2];
#pragma unroll
  for (int Qq = 0; Qq < 4; ++Qq) {
    bq[Qq][0] = bias[Qq * 256 + q * 64 + 2 * e5];
    bq[Qq][1] = bias[Qq * 256 + q * 64 + 2 * e5 + 1];
  }

  // per-group state (statically indexed via unrolled G loop)
  float cc[4][2] = {{0.f, 0.f}, {0.f, 0.f}, {0.f, 0.f}, {0.f, 0.f}};
  float hh[4][2] = {{0.f, 0.f}, {0.f, 0.f}, {0.f, 0.f}, {0.f, 0.f}};

  const int prow = w * 2 + (l >> 5);    // this wave's poll row (local 0..15)
  const int pswz = (prow & 7) << 4;
  const int swzf = (l15 & 7) << 4;

  for (int t = 0; t < L_; ++t) {
    const unsigned want = (unsigned)t;
    const int parR = (t + 1) & 1;       // read parity (h(t-1) slots)
    const int parW = t & 1;             // write parity (h(t) slots)

#pragma unroll
    for (int G = 0; G < 4; ++G) {
      const int row0 = G * 16;

      // ---- xg + mask for (G, t) (hidden under poll)
      const u32x4 xq = *(const u32x4*)(xgw +
          (((((size_t)t * 4 + G) * 4 + q) * 16 + em) * 32 + e5) * 4);
      const unsigned char mk = mask8[t * 64 + row0 + em];

      // ---- poll own 2 rows of group G's h(t-1): published ~T_iter ago
      {
        const char* hp = htag + parR * 65536 + (row0 + prow) * 1024 + (l & 31) * 32;
        u32x4 qa, qb;
        int spins = 0;
        while (true) {
          asm volatile("global_load_dwordx4 %0, %2, off sc0 sc1\n\t"
                       "global_load_dwordx4 %1, %2, off offset:16 sc0 sc1\n\t"
                       "s_waitcnt vmcnt(0)"
                       : "=&v"(qa), "=&v"(qb) : "v"(hp) : "memory");
          unsigned mn = qa.y < qa.w ? qa.y : qa.w;
          mn = qb.y < mn ? qb.y : mn;
          mn = qb.w < mn ? qb.w : mn;
          if (__all((int)(mn >= want))) break;
          if (++spins > 16384) break;   // fail-safe: never hang
        }
        union { unsigned u[4]; s16x8 v; } hcv;
        hcv.u[0] = qa.x; hcv.u[1] = qa.z; hcv.u[2] = qb.x; hcv.u[3] = qb.z;
        *(s16x8*)(hl + prow * 512 + (((l & 31) * 16) ^ pswz)) = hcv.v;
      }
      asm volatile("s_waitcnt lgkmcnt(0)" ::: "memory");
      __builtin_amdgcn_s_barrier();     // A: h staged (also guards hl reuse)

      // ---- A-frags from swizzled LDS + 16 MFMA (8 kk x 2 n-strips)
      f32x4 acc0 = {0.f, 0.f, 0.f, 0.f}, acc1 = {0.f, 0.f, 0.f, 0.f};
      s16x8 hf[8];
#pragma unroll
      for (int kk = 0; kk < 8; ++kk)
        hf[kk] = *(const s16x8*)(hl + l15 * 512 + ((kk * 64 + lhi * 16) ^ swzf));
#pragma unroll
      for (int kk = 0; kk < 8; ++kk) {
        acc0 = __builtin_amdgcn_mfma_f32_16x16x32_bf16(hf[kk], ur[kk * 2 + 0], acc0, 0, 0, 0);
        acc1 = __builtin_amdgcn_mfma_f32_16x16x32_bf16(hf[kk], ur[kk * 2 + 1], acc1, 0, 0, 0);
      }

      // ---- gates to LDS: sg[Q][row][col], col = sgs*32 + {0,16} + l15
#pragma unroll
      for (int r = 0; r < 4; ++r) {
        sg[(Q * 16 + lhi * 4 + r) * 66 + sgs * 32 + l15]      = acc0[r];
        sg[(Q * 16 + lhi * 4 + r) * 66 + sgs * 32 + 16 + l15] = acc1[r];
      }
      asm volatile("s_waitcnt lgkmcnt(0)" ::: "memory");
      __builtin_amdgcn_s_barrier();     // B: gates ready (also guards sg reuse)

      // ---- elementwise LSTM: 2 cells (row em, d = q*64 + 2*e5 + {0,1})
      {
        float gv[4][2];
#pragma unroll
        for (int Qq = 0; Qq < 4; ++Qq) {
          gv[Qq][0] = sg[(Qq * 16 + em) * 66 + 2 * e5];
          gv[Qq][1] = sg[(Qq * 16 + em) * 66 + 2 * e5 + 1];
        }
        const bool upd = (mk != 0);
        unsigned short hsv[2];
#pragma unroll
        for (int b = 0; b < 2; ++b) {
          float xi = b ? bh(xq.x) : bl(xq.x);
          float xf = b ? bh(xq.y) : bl(xq.y);
          float xc = b ? bh(xq.z) : bl(xq.z);
          float xo = b ? bh(xq.w) : bl(xq.w);
          float gi = gv[0][b] + xi + bq[0][b];
          float gf = gv[1][b] + xf + bq[1][b];
          float gc = gv[2][b] + xc + bq[2][b];
          float go = gv[3][b] + xo + bq[3][b];
          float i_ = fsigmoid(gi), f_ = fsigmoid(gf), o_ = fsigmoid(go);
          float cn = f_ * cc[G][b] + i_ * ftanh(gc);
          float hn = o_ * ftanh(cn);
          cc[G][b] = upd ? cn : cc[G][b];
          hh[G][b] = upd ? hn : hh[G][b];
          hsv[b] = __bfloat16_as_ushort(__float2bfloat16(hh[G][b]));
        }
        // publish tagged granule {2xbf16, t+1} (sc0sc1, COALESCED, f&f)
        u32x2 gr;
        gr.x = (unsigned)hsv[0] | ((unsigned)hsv[1] << 16);
        gr.y = (unsigned)(t + 1);
        char* pw = htag + parW * 65536 + (row0 + em) * 1024 + (q * 32 + e5) * 8;
        asm volatile("global_store_dwordx2 %0, %1, off sc0 sc1"
                     :: "v"(pw), "v"(gr) : "memory");
        // output store (fire-and-forget, off the critical path)
        float* op = out + ((size_t)(row0 + em) * L_ + t) * D_ + q * 64 + 2 * e5;
        op[0] = hh[G][0];
        op[1] = hh[G][1];
      }
    }
  }

  // signal heaters
  if (tid == 0) {
    unsigned one = 1u;
    unsigned* df = donef + q;
    asm volatile("global_store_dword %0, %1, off sc0 sc1"
                 :: "v"(df), "v"(one) : "memory");
  }
}

extern "C" void kernel_launch(void* const* d_in, const int* in_sizes, int n_in,
                              void* d_out, int out_size, void* d_ws, size_t ws_size,
                              hipStream_t stream) {
  const int*   ctx  = (const int*)d_in[0];
  const float* emb  = (const float*)d_in[1];
  const float* W    = (const float*)d_in[2];
  const float* U    = (const float*)d_in[3];
  const float* bias = (const float*)d_in[4];
  float* out = (float*)d_out;

  char* ws = (char*)d_ws;
  __hip_bfloat16* embb = (__hip_bfloat16*)(ws + OFF_EMBB);
  __hip_bfloat16* Wt   = (__hip_bfloat16*)(ws + OFF_WT);
  __hip_bfloat16* Uf   = (__hip_bfloat16*)(ws + OFF_UF);
  char*           htag = ws + OFF_HTAG;
  unsigned*       donef = (unsigned*)(ws + OFF_DONE);
  unsigned*       xgw  = (unsigned*)(ws + OFF_XG);
  unsigned char*  m8   = (unsigned char*)(ws + OFF_WT);   // reuse Wt after xg

  // per-launch resets (graph replays don't re-poison ws)
  hipMemsetAsync(htag, 0, 131072, stream);   // tag 0 == "h(-1)=0 ready"
  hipMemsetAsync(donef, 0, 64, stream);

  hipFuncSetAttribute((const void*)scan_kernel,
                      hipFuncAttributeMaxDynamicSharedMemorySize, SMEM_TOTAL);

  prep_kernel<<<1024, 256, 0, stream>>>(emb, W, U, embb, Wt, Uf);
  xg_kernel<<<512, 256, 0, stream>>>(ctx, embb, Wt, xgw);
  mask_kernel<<<128, 256, 0, stream>>>(ctx, m8);           // overwrites Wt (dead)
  scan_kernel<<<256, 512, SMEM_TOTAL, stream>>>(bias, Uf, xgw, m8, donef, htag, out);
}